// Round 7
// baseline (73.839 us; speedup 1.0000x reference)
//
#include <hip/hip_runtime.h>
#include <math.h>

#define BS   4
#define V    4096
#define NB   50
#define IC   64
#define OC   64
#define SUP  4
#define WCOL 320
#define WT_STRIDE 72     // shorts; 144B row -> 2-way LDS bank aliasing (free)
#define TBL_STRIDE 128   // dwords per row: dxdy[50] @ +0, dzw[50] @ +64

typedef float f32x2 __attribute__((ext_vector_type(2)));
typedef float f32x4 __attribute__((ext_vector_type(4)));
typedef short s16x8 __attribute__((ext_vector_type(8)));

__device__ inline unsigned short bf16r(float f) {          // RNE f32->bf16
    unsigned u = __builtin_bit_cast(unsigned, f);
    u += 0x7FFFu + ((u >> 16) & 1u);
    return (unsigned short)(u >> 16);
}
__device__ inline float bflo(unsigned u) {   // lo16 bf16 -> f32
    return __builtin_bit_cast(float, u << 16);
}
__device__ inline float bfhi(unsigned u) {   // hi16 bf16 -> f32
    return __builtin_bit_cast(float, u & 0xffff0000u);
}
__device__ inline f32x2 pk_mul(f32x2 a, f32x2 b) {
    f32x2 d; asm("v_pk_mul_f32 %0, %1, %2" : "=v"(d) : "v"(a), "v"(b)); return d;
}
__device__ inline f32x2 pk_fma(f32x2 a, f32x2 b, f32x2 c) {
    f32x2 d; asm("v_pk_fma_f32 %0, %1, %2, %3" : "=v"(d) : "v"(a), "v"(b), "v"(c)); return d;
}

// ---------------------------------------------------------------------------
// Kernel 1 (MFMA): feature_out = fm @ W + bias.
//   out[row*64 + c]          = feature_out[row][c]            (center -> d_out)
//   fo_s[(row*64 + c)*4 + s] = bf16(feature_out[row][64+s*64+c])
// ---------------------------------------------------------------------------
__global__ __launch_bounds__(256) void feat_kernel(
    const float* __restrict__ fm,    // (16384, 64)
    const float* __restrict__ W,     // (64, 320)
    const float* __restrict__ bias,  // (320,)
    float* __restrict__ out,         // (16384, 64)  center slice
    unsigned short* __restrict__ fo_s)
{
    __shared__ unsigned short wt[WCOL * WT_STRIDE];  // wt[col][k], 45 KB
    const int t = threadIdx.x;

#pragma unroll
    for (int i = 0; i < 20; ++i) {
        const int idx4 = t + i * 256;
        const int e    = idx4 * 4;
        const int k    = e / WCOL;
        const int col  = e - k * WCOL;
        const float4 v = reinterpret_cast<const float4*>(W)[idx4];
        wt[(col + 0) * WT_STRIDE + k] = bf16r(v.x);
        wt[(col + 1) * WT_STRIDE + k] = bf16r(v.y);
        wt[(col + 2) * WT_STRIDE + k] = bf16r(v.z);
        wt[(col + 3) * WT_STRIDE + k] = bf16r(v.w);
    }
    __syncthreads();

    const int w   = t >> 6;
    const int l   = t & 63;
    const int rlo = l & 15;
    const int kg  = l >> 4;
    const int row = blockIdx.x * 64 + w * 16 + rlo;

    const float* fr = &fm[row * IC + kg * 8];
    s16x8 a0, a1;
#pragma unroll
    for (int e = 0; e < 8; ++e) {
        a0[e] = (short)bf16r(fr[e]);
        a1[e] = (short)bf16r(fr[32 + e]);
    }

    const int drow0 = blockIdx.x * 64 + w * 16 + kg * 4;
#pragma unroll
    for (int ct = 0; ct < 20; ++ct) {
        const int col = ct * 16 + rlo;
        const s16x8 b0 = *reinterpret_cast<const s16x8*>(&wt[col * WT_STRIDE + kg * 8]);
        const s16x8 b1 = *reinterpret_cast<const s16x8*>(&wt[col * WT_STRIDE + 32 + kg * 8]);
        f32x4 acc = {0.f, 0.f, 0.f, 0.f};
        acc = __builtin_amdgcn_mfma_f32_16x16x32_bf16(a0, b0, acc, 0, 0, 0);
        acc = __builtin_amdgcn_mfma_f32_16x16x32_bf16(a1, b1, acc, 0, 0, 0);
        const float bv = bias[col];
        if (ct < 4) {
#pragma unroll
            for (int r = 0; r < 4; ++r)
                out[(drow0 + r) * OC + col] = acc[r] + bv;
        } else {
            const int cc = (col - OC) & 63;
            const int s  = (col - OC) >> 6;
#pragma unroll
            for (int r = 0; r < 4; ++r)
                fo_s[((drow0 + r) * OC + cc) * SUP + s] = bf16r(acc[r] + bv);
        }
    }
}

// ---------------------------------------------------------------------------
// Kernel 2 (prep): per (row, j) wave-uniform data -> packed bf16 global table.
//   tbl[row*128 +      j] = {bf16(dy) << 16 | bf16(dx)}
//   tbl[row*128 + 64 + j] = {bf16(w)  << 16 | bf16(dz)}
// ---------------------------------------------------------------------------
__global__ __launch_bounds__(256) void prep_kernel(
    const int*   __restrict__ nidx,   // (BS, V, 50)
    const float* __restrict__ verts,  // (BS, V, 3)
    const float* __restrict__ nval,   // (BS, V, 50)
    unsigned* __restrict__ tbl)
{
    const int wv  = threadIdx.x >> 6;
    const int c   = threadIdx.x & 63;
    const int row = blockIdx.x * 4 + wv;
    const int b   = row >> 12;

    const float nv = (c < NB) ? nval[(size_t)row * NB + c] : 0.f;
    float ss = nv * nv;
#pragma unroll
    for (int o = 32; o > 0; o >>= 1) ss += __shfl_xor(ss, o);
    const float wn = nv * (1.f / fmaxf(sqrtf(ss), 1e-12f));

    if (c < NB) {
        const int idx = nidx[(size_t)row * NB + c];
        const float* vn = &verts[(size_t)(b * V + idx) * 3];
        const float* vc = &verts[(size_t)row * 3];
        float dx = vn[0] - vc[0], dy = vn[1] - vc[1], dz = vn[2] - vc[2];
        const float inv = 1.f / fmaxf(sqrtf(dx * dx + dy * dy + dz * dz), 1e-12f);
        dx *= inv; dy *= inv; dz *= inv;
        tbl[(size_t)row * TBL_STRIDE + c]      = ((unsigned)bf16r(dy) << 16) | bf16r(dx);
        tbl[(size_t)row * TBL_STRIDE + 64 + c] = ((unsigned)bf16r(wn) << 16) | bf16r(dz);
    }
}

// ---------------------------------------------------------------------------
// Kernel 3 (conv): NO LDS in the loop. Per wave = one row; per j:
//   3 uniform global loads (idx, dxdy, dzw; L1 broadcast) + 1 gather (uint2)
//   + packed-pair VALU math. 3-stage pipeline in chunks of 5.
// ---------------------------------------------------------------------------
__global__ __launch_bounds__(256) void conv_kernel(
    const int*      __restrict__ nidx,   // (BS, V, 50)
    const float*    __restrict__ dirs,   // (3, 256)
    const unsigned* __restrict__ tbl,    // (16384, 128)
    const unsigned short* __restrict__ fo_s, // (16384, 64, 4) bf16
    float* __restrict__ out)             // (16384, 64) holds center on entry
{
    const int bid = blockIdx.x;                     // 0..4095
    const int swz = ((bid & 7) << 9) + (bid >> 3);  // XCD bijection on 4096
    const int wv  = threadIdx.x >> 6;
    const int c   = threadIdx.x & 63;
    const int row = swz * 4 + wv;                   // same batch for all 4 waves
    const int b   = swz >> 10;

    // per-lane normalized direction columns, packed for pk ops
    f32x2 cx01, cx23, cy01, cy23, cz01, cz23;
    {
        float sx[4], sy[4], sz[4];
#pragma unroll
        for (int s = 0; s < 4; ++s) {
            const int col = s * 64 + c;
            const float d0 = dirs[col], d1 = dirs[256 + col], d2 = dirs[512 + col];
            const float inv = 1.f / fmaxf(sqrtf(d0 * d0 + d1 * d1 + d2 * d2), 1e-12f);
            sx[s] = d0 * inv; sy[s] = d1 * inv; sz[s] = d2 * inv;
        }
        cx01 = (f32x2){sx[0], sx[1]}; cx23 = (f32x2){sx[2], sx[3]};
        cy01 = (f32x2){sy[0], sy[1]}; cy23 = (f32x2){sy[2], sy[3]};
        cz01 = (f32x2){sz[0], sz[1]}; cz23 = (f32x2){sz[2], sz[3]};
    }

    const float center = out[(size_t)row * OC + c];

    const char* base = (const char*)fo_s + (size_t)b * ((size_t)V * OC * SUP * 2);
    const unsigned c8 = (unsigned)(c << 3);
    const int*      __restrict__ nrow = nidx + (size_t)row * NB;
    const unsigned* __restrict__ trow = tbl  + (size_t)row * TBL_STRIDE;

    f32x2 acc = {0.f, 0.f};
    int      iA[5], iB[5];
    unsigned x0xy[5], x0zw[5], x1xy[5], x1zw[5], x2xy[5], x2zw[5];
    uint2    g0[5], g1[5];

#define TT(k, Xxy, Xzw, I) _Pragma("unroll") for (int u = 0; u < 5; ++u) { \
        I[u]   = nrow[(k) * 5 + u]; \
        Xxy[u] = trow[(k) * 5 + u]; \
        Xzw[u] = trow[64 + (k) * 5 + u]; }

#define GG(I, Gb) _Pragma("unroll") for (int u = 0; u < 5; ++u) { \
        Gb[u] = *reinterpret_cast<const uint2*>(base + (((unsigned)I[u]) << 9) + c8); }

#define CM(Xxy, Xzw, Gb) _Pragma("unroll") for (int u = 0; u < 5; ++u) { \
        const unsigned pxy = Xxy[u], pzw = Xzw[u]; \
        f32x2 vdx; vdx.x = bflo(pxy); vdx.y = vdx.x; \
        f32x2 vdy; vdy.x = bfhi(pxy); vdy.y = vdy.x; \
        f32x2 vdz; vdz.x = bflo(pzw); vdz.y = vdz.x; \
        f32x2 vw;  vw.x  = bfhi(pzw); vw.y  = vw.x; \
        f32x2 t01 = pk_fma(vdx, cx01, pk_fma(vdy, cy01, pk_mul(vdz, cz01))); \
        f32x2 t23 = pk_fma(vdx, cx23, pk_fma(vdy, cy23, pk_mul(vdz, cz23))); \
        t01.x = fmaxf(t01.x, 0.f); t01.y = fmaxf(t01.y, 0.f); \
        t23.x = fmaxf(t23.x, 0.f); t23.y = fmaxf(t23.y, 0.f); \
        f32x2 f01, f23; \
        f01.x = bflo(Gb[u].x); f01.y = bfhi(Gb[u].x); \
        f23.x = bflo(Gb[u].y); f23.y = bfhi(Gb[u].y); \
        f32x2 m = pk_mul(t01, f01); \
        m = pk_fma(t23, f23, m); \
        acc = pk_fma(m, vw, acc); }

    // 3-stage pipeline over 10 chunks of 5 neighbors.
    TT(0, x0xy, x0zw, iA); TT(1, x1xy, x1zw, iB);
    GG(iA, g0);            TT(2, x2xy, x2zw, iA);
    GG(iB, g1);            CM(x0xy, x0zw, g0);
    TT(3, x0xy, x0zw, iB); GG(iA, g0); CM(x1xy, x1zw, g1);
    TT(4, x1xy, x1zw, iA); GG(iB, g1); CM(x2xy, x2zw, g0);
    TT(5, x2xy, x2zw, iB); GG(iA, g0); CM(x0xy, x0zw, g1);
    TT(6, x0xy, x0zw, iA); GG(iB, g1); CM(x1xy, x1zw, g0);
    TT(7, x1xy, x1zw, iB); GG(iA, g0); CM(x2xy, x2zw, g1);
    TT(8, x2xy, x2zw, iA); GG(iB, g1); CM(x0xy, x0zw, g0);
    TT(9, x0xy, x0zw, iB); GG(iA, g0); CM(x1xy, x1zw, g1);
                           GG(iB, g1); CM(x2xy, x2zw, g0);
                                       CM(x0xy, x0zw, g1);
#undef TT
#undef GG
#undef CM

    out[(size_t)row * OC + c] = center + acc.x + acc.y;
}

// ---------------------------------------------------------------------------
extern "C" void kernel_launch(void* const* d_in, const int* in_sizes, int n_in,
                              void* d_out, int out_size, void* d_ws, size_t ws_size,
                              hipStream_t stream) {
    const int*   nidx  = (const int*)  d_in[0];
    const float* verts = (const float*)d_in[1];
    const float* fm    = (const float*)d_in[2];
    const float* nval  = (const float*)d_in[3];
    const float* W     = (const float*)d_in[4];
    const float* bias  = (const float*)d_in[5];
    const float* dirs  = (const float*)d_in[6];
    float*       out   = (float*)d_out;

    unsigned short* fo_s = (unsigned short*)d_ws;                          // 8 MB
    unsigned*       tbl  = (unsigned*)((char*)d_ws + (((size_t)8) << 20)); // 8 MB

    feat_kernel<<<(BS * V) / 64, 256, 0, stream>>>(fm, W, bias, out, fo_s);
    prep_kernel<<<(BS * V) / 4, 256, 0, stream>>>(nidx, verts, nval, tbl);
    conv_kernel<<<(BS * V) / 4, 256, 0, stream>>>(nidx, dirs, tbl, fo_s, out);
}

// Round 8
// 72.165 us; speedup vs baseline: 1.0232x; 1.0232x over previous
//
#include <hip/hip_runtime.h>
#include <math.h>

#define BS   4
#define V    4096
#define NB   50
#define IC   64
#define OC   64
#define SUP  4
#define WCOL 320
#define WT_STRIDE 72     // shorts; 144B row -> 2-way LDS bank aliasing (free)

typedef float    f32x2 __attribute__((ext_vector_type(2)));
typedef float    f32x4 __attribute__((ext_vector_type(4)));
typedef short    s16x8 __attribute__((ext_vector_type(8)));
typedef _Float16 h16x4 __attribute__((ext_vector_type(4)));

__device__ inline unsigned short bf16r(float f) {          // RNE f32->bf16
    unsigned u = __builtin_bit_cast(unsigned, f);
    u += 0x7FFFu + ((u >> 16) & 1u);
    return (unsigned short)(u >> 16);
}
__device__ inline float bflo(unsigned u) {   // lo16 bf16 -> f32
    return __builtin_bit_cast(float, u << 16);
}
__device__ inline float bfhi(unsigned u) {   // hi16 bf16 -> f32
    return __builtin_bit_cast(float, u & 0xffff0000u);
}

// ---------------------------------------------------------------------------
// Kernel 1 (MFMA): feature_out = fm @ W + bias.
//   out[row*64 + c]          = feature_out[row][c]            (center -> d_out)
//   fo_s[(row*64 + c)*4 + s] = bf16(feature_out[row][64+s*64+c])
// ---------------------------------------------------------------------------
__global__ __launch_bounds__(256) void feat_kernel(
    const float* __restrict__ fm,    // (16384, 64)
    const float* __restrict__ W,     // (64, 320)
    const float* __restrict__ bias,  // (320,)
    float* __restrict__ out,         // (16384, 64)  center slice
    unsigned short* __restrict__ fo_s)
{
    __shared__ unsigned short wt[WCOL * WT_STRIDE];  // wt[col][k], 45 KB
    const int t = threadIdx.x;

#pragma unroll
    for (int i = 0; i < 20; ++i) {
        const int idx4 = t + i * 256;
        const int e    = idx4 * 4;
        const int k    = e / WCOL;
        const int col  = e - k * WCOL;
        const float4 v = reinterpret_cast<const float4*>(W)[idx4];
        wt[(col + 0) * WT_STRIDE + k] = bf16r(v.x);
        wt[(col + 1) * WT_STRIDE + k] = bf16r(v.y);
        wt[(col + 2) * WT_STRIDE + k] = bf16r(v.z);
        wt[(col + 3) * WT_STRIDE + k] = bf16r(v.w);
    }
    __syncthreads();

    const int w   = t >> 6;
    const int l   = t & 63;
    const int rlo = l & 15;
    const int kg  = l >> 4;
    const int row = blockIdx.x * 64 + w * 16 + rlo;

    const float* fr = &fm[row * IC + kg * 8];
    s16x8 a0, a1;
#pragma unroll
    for (int e = 0; e < 8; ++e) {
        a0[e] = (short)bf16r(fr[e]);
        a1[e] = (short)bf16r(fr[32 + e]);
    }

    const int drow0 = blockIdx.x * 64 + w * 16 + kg * 4;
#pragma unroll
    for (int ct = 0; ct < 20; ++ct) {
        const int col = ct * 16 + rlo;
        const s16x8 b0 = *reinterpret_cast<const s16x8*>(&wt[col * WT_STRIDE + kg * 8]);
        const s16x8 b1 = *reinterpret_cast<const s16x8*>(&wt[col * WT_STRIDE + 32 + kg * 8]);
        f32x4 acc = {0.f, 0.f, 0.f, 0.f};
        acc = __builtin_amdgcn_mfma_f32_16x16x32_bf16(a0, b0, acc, 0, 0, 0);
        acc = __builtin_amdgcn_mfma_f32_16x16x32_bf16(a1, b1, acc, 0, 0, 0);
        const float bv = bias[col];
        if (ct < 4) {
#pragma unroll
            for (int r = 0; r < 4; ++r)
                out[(drow0 + r) * OC + col] = acc[r] + bv;
        } else {
            const int cc = (col - OC) & 63;
            const int s  = (col - OC) >> 6;
#pragma unroll
            for (int r = 0; r < 4; ++r)
                fo_s[((drow0 + r) * OC + cc) * SUP + s] = bf16r(acc[r] + bv);
        }
    }
}

// ---------------------------------------------------------------------------
// Kernel 2 (prep): per (row, j):
//   tblH[row*50 + j] = f16x4 {dx, dy, dz, w}   (8 B)
//   tblO[row*50 + j] = idx << 9                (pre-shifted gather byte offset)
// ---------------------------------------------------------------------------
__global__ __launch_bounds__(256) void prep_kernel(
    const int*   __restrict__ nidx,   // (BS, V, 50)
    const float* __restrict__ verts,  // (BS, V, 3)
    const float* __restrict__ nval,   // (BS, V, 50)
    h16x4*    __restrict__ tblH,
    unsigned* __restrict__ tblO)
{
    const int wv  = threadIdx.x >> 6;
    const int c   = threadIdx.x & 63;
    const int row = blockIdx.x * 4 + wv;
    const int b   = row >> 12;

    const float nv = (c < NB) ? nval[(size_t)row * NB + c] : 0.f;
    float ss = nv * nv;
#pragma unroll
    for (int o = 32; o > 0; o >>= 1) ss += __shfl_xor(ss, o);
    const float wn = nv * (1.f / fmaxf(sqrtf(ss), 1e-12f));

    if (c < NB) {
        const int idx = nidx[(size_t)row * NB + c];
        const float* vn = &verts[(size_t)(b * V + idx) * 3];
        const float* vc = &verts[(size_t)row * 3];
        float dx = vn[0] - vc[0], dy = vn[1] - vc[1], dz = vn[2] - vc[2];
        const float inv = 1.f / fmaxf(sqrtf(dx * dx + dy * dy + dz * dz), 1e-12f);
        dx *= inv; dy *= inv; dz *= inv;
        h16x4 hv = { (_Float16)dx, (_Float16)dy, (_Float16)dz, (_Float16)wn };
        tblH[(size_t)row * NB + c] = hv;
        tblO[(size_t)row * NB + c] = ((unsigned)idx) << 9;
    }
}

// ---------------------------------------------------------------------------
// Kernel 3 (conv): per wave = one row. Per j: 3 VMEM (tblH 8B, tblO 4B,
// gather 8B) + plain-C f32x4 packed math (no inline asm -> no marshaling
// movs, op_sel broadcast folding). acc components = the 4 supports.
// ---------------------------------------------------------------------------
__global__ __launch_bounds__(256) void conv_kernel(
    const float*    __restrict__ dirs,   // (3, 256)
    const h16x4*    __restrict__ tblH,   // (16384, 50)
    const unsigned* __restrict__ tblO,   // (16384, 50)
    const unsigned short* __restrict__ fo_s, // (16384, 64, 4) bf16
    float* __restrict__ out)             // (16384, 64) holds center on entry
{
    const int bid = blockIdx.x;                     // 0..4095
    const int swz = ((bid & 7) << 9) + (bid >> 3);  // XCD bijection on 4096
    const int wv  = threadIdx.x >> 6;
    const int c   = threadIdx.x & 63;
    const int row = swz * 4 + wv;                   // same batch for all 4 waves
    const int b   = swz >> 10;

    // per-lane normalized direction columns, component s of cx4 = support s
    f32x4 cx4, cy4, cz4;
#pragma unroll
    for (int s = 0; s < 4; ++s) {
        const int col = s * 64 + c;
        const float d0 = dirs[col], d1 = dirs[256 + col], d2 = dirs[512 + col];
        const float inv = 1.f / fmaxf(sqrtf(d0 * d0 + d1 * d1 + d2 * d2), 1e-12f);
        cx4[s] = d0 * inv; cy4[s] = d1 * inv; cz4[s] = d2 * inv;
    }

    const float center = out[(size_t)row * OC + c];

    const char* baseb = (const char*)fo_s + (size_t)b * ((size_t)V * OC * SUP * 2);
    const unsigned c8 = (unsigned)(c << 3);
    const h16x4*    __restrict__ hrow = tblH + (size_t)row * NB;
    const unsigned* __restrict__ orow = tblO + (size_t)row * NB;

    f32x4 acc = {0.f, 0.f, 0.f, 0.f};
    h16x4    h0[5], h1[5], h2[5];
    unsigned o0[5], o1[5];
    uint2    g0[5], g1[5];

#define TT(k, H, O) _Pragma("unroll") for (int u = 0; u < 5; ++u) { \
        H[u] = hrow[(k) * 5 + u]; \
        O[u] = orow[(k) * 5 + u]; }

#define GG(O, G) _Pragma("unroll") for (int u = 0; u < 5; ++u) { \
        G[u] = *reinterpret_cast<const uint2*>(baseb + (O[u] + c8)); }

#define CM(H, G) _Pragma("unroll") for (int u = 0; u < 5; ++u) { \
        const float dx = (float)H[u].x, dy = (float)H[u].y; \
        const float dz = (float)H[u].z, wj = (float)H[u].w; \
        f32x4 t = cx4 * dx + cy4 * dy + cz4 * dz; \
        t.x = fmaxf(t.x, 0.f); t.y = fmaxf(t.y, 0.f); \
        t.z = fmaxf(t.z, 0.f); t.w = fmaxf(t.w, 0.f); \
        f32x4 f; \
        f.x = bflo(G[u].x); f.y = bfhi(G[u].x); \
        f.z = bflo(G[u].y); f.w = bfhi(G[u].y); \
        acc += (t * wj) * f; }

    // 3-stage pipeline over 10 chunks of 5 neighbors.
    TT(0, h0, o0); TT(1, h1, o1);
    GG(o0, g0);    TT(2, h2, o0);
    GG(o1, g1);    CM(h0, g0);
    TT(3, h0, o1); GG(o0, g0); CM(h1, g1);
    TT(4, h1, o0); GG(o1, g1); CM(h2, g0);
    TT(5, h2, o1); GG(o0, g0); CM(h0, g1);
    TT(6, h0, o0); GG(o1, g1); CM(h1, g0);
    TT(7, h1, o1); GG(o0, g0); CM(h2, g1);
    TT(8, h2, o0); GG(o1, g1); CM(h0, g0);
    TT(9, h0, o1); GG(o0, g0); CM(h1, g1);
                   GG(o1, g1); CM(h2, g0);
                               CM(h0, g1);
#undef TT
#undef GG
#undef CM

    out[(size_t)row * OC + c] = center + acc.x + acc.y + acc.z + acc.w;
}

// ---------------------------------------------------------------------------
extern "C" void kernel_launch(void* const* d_in, const int* in_sizes, int n_in,
                              void* d_out, int out_size, void* d_ws, size_t ws_size,
                              hipStream_t stream) {
    const int*   nidx  = (const int*)  d_in[0];
    const float* verts = (const float*)d_in[1];
    const float* fm    = (const float*)d_in[2];
    const float* nval  = (const float*)d_in[3];
    const float* W     = (const float*)d_in[4];
    const float* bias  = (const float*)d_in[5];
    const float* dirs  = (const float*)d_in[6];
    float*       out   = (float*)d_out;

    // ws layout: fo_s 8 MiB | tblH 6.25 MiB | tblO 3.125 MiB  (18.2 MiB total)
    unsigned short* fo_s = (unsigned short*)d_ws;
    h16x4*    tblH = (h16x4*)((char*)d_ws + 8388608);
    unsigned* tblO = (unsigned*)((char*)d_ws + 8388608 + 6553600);

    feat_kernel<<<(BS * V) / 64, 256, 0, stream>>>(fm, W, bias, out, fo_s);
    prep_kernel<<<(BS * V) / 4, 256, 0, stream>>>(nidx, verts, nval, tblH, tblO);
    conv_kernel<<<(BS * V) / 4, 256, 0, stream>>>(dirs, tblH, tblO, fo_s, out);
}

// Round 9
// 68.794 us; speedup vs baseline: 1.0733x; 1.0490x over previous
//
#include <hip/hip_runtime.h>
#include <math.h>

#define BS   4
#define V    4096
#define NB   50
#define IC   64
#define OC   64
#define SUP  4
#define WCOL 320
#define WT_STRIDE 72     // shorts; 144B row -> 2-way LDS bank aliasing (free)

typedef float    f32x4 __attribute__((ext_vector_type(4)));
typedef short    s16x8 __attribute__((ext_vector_type(8)));
typedef _Float16 h16x2 __attribute__((ext_vector_type(2)));

__device__ inline unsigned short bf16r(float f) {          // RNE f32->bf16
    unsigned u = __builtin_bit_cast(unsigned, f);
    u += 0x7FFFu + ((u >> 16) & 1u);
    return (unsigned short)(u >> 16);
}
__device__ inline float bflo(unsigned u) {   // lo16 bf16 -> f32
    return __builtin_bit_cast(float, u << 16);
}
__device__ inline float bfhi(unsigned u) {   // hi16 bf16 -> f32
    return __builtin_bit_cast(float, u & 0xffff0000u);
}

// ---------------------------------------------------------------------------
// Kernel 1 (MFMA): feature_out = fm @ W + bias.
//   out[row*64 + c]          = feature_out[row][c]            (center -> d_out)
//   fo_s[(row*64 + c)*4 + s] = bf16(feature_out[row][64+s*64+c])
// ---------------------------------------------------------------------------
__global__ __launch_bounds__(256) void feat_kernel(
    const float* __restrict__ fm,    // (16384, 64)
    const float* __restrict__ W,     // (64, 320)
    const float* __restrict__ bias,  // (320,)
    float* __restrict__ out,         // (16384, 64)  center slice
    unsigned short* __restrict__ fo_s)
{
    __shared__ unsigned short wt[WCOL * WT_STRIDE];  // wt[col][k], 45 KB
    const int t = threadIdx.x;

#pragma unroll
    for (int i = 0; i < 20; ++i) {
        const int idx4 = t + i * 256;
        const int e    = idx4 * 4;
        const int k    = e / WCOL;
        const int col  = e - k * WCOL;
        const float4 v = reinterpret_cast<const float4*>(W)[idx4];
        wt[(col + 0) * WT_STRIDE + k] = bf16r(v.x);
        wt[(col + 1) * WT_STRIDE + k] = bf16r(v.y);
        wt[(col + 2) * WT_STRIDE + k] = bf16r(v.z);
        wt[(col + 3) * WT_STRIDE + k] = bf16r(v.w);
    }
    __syncthreads();

    const int w   = t >> 6;
    const int l   = t & 63;
    const int rlo = l & 15;
    const int kg  = l >> 4;
    const int row = blockIdx.x * 64 + w * 16 + rlo;

    const float* fr = &fm[row * IC + kg * 8];
    s16x8 a0, a1;
#pragma unroll
    for (int e = 0; e < 8; ++e) {
        a0[e] = (short)bf16r(fr[e]);
        a1[e] = (short)bf16r(fr[32 + e]);
    }

    const int drow0 = blockIdx.x * 64 + w * 16 + kg * 4;
#pragma unroll
    for (int ct = 0; ct < 20; ++ct) {
        const int col = ct * 16 + rlo;
        const s16x8 b0 = *reinterpret_cast<const s16x8*>(&wt[col * WT_STRIDE + kg * 8]);
        const s16x8 b1 = *reinterpret_cast<const s16x8*>(&wt[col * WT_STRIDE + 32 + kg * 8]);
        f32x4 acc = {0.f, 0.f, 0.f, 0.f};
        acc = __builtin_amdgcn_mfma_f32_16x16x32_bf16(a0, b0, acc, 0, 0, 0);
        acc = __builtin_amdgcn_mfma_f32_16x16x32_bf16(a1, b1, acc, 0, 0, 0);
        const float bv = bias[col];
        if (ct < 4) {
#pragma unroll
            for (int r = 0; r < 4; ++r)
                out[(drow0 + r) * OC + col] = acc[r] + bv;
        } else {
            const int cc = (col - OC) & 63;
            const int s  = (col - OC) >> 6;
#pragma unroll
            for (int r = 0; r < 4; ++r)
                fo_s[((drow0 + r) * OC + cc) * SUP + s] = bf16r(acc[r] + bv);
        }
    }
}

// ---------------------------------------------------------------------------
// Kernel 2 (prep): per (row, j):
//   tblH[row*50 + j] = uint2 { f16(dx)|f16(dy), f16(dz)|f16(w) }
//   tblO[row*50 + j] = idx << 9   (pre-shifted gather byte offset)
// ---------------------------------------------------------------------------
__global__ __launch_bounds__(256) void prep_kernel(
    const int*   __restrict__ nidx,   // (BS, V, 50)
    const float* __restrict__ verts,  // (BS, V, 3)
    const float* __restrict__ nval,   // (BS, V, 50)
    uint2*    __restrict__ tblH,
    unsigned* __restrict__ tblO)
{
    const int wv  = threadIdx.x >> 6;
    const int c   = threadIdx.x & 63;
    const int row = blockIdx.x * 4 + wv;
    const int b   = row >> 12;

    const float nv = (c < NB) ? nval[(size_t)row * NB + c] : 0.f;
    float ss = nv * nv;
#pragma unroll
    for (int o = 32; o > 0; o >>= 1) ss += __shfl_xor(ss, o);
    const float wn = nv * (1.f / fmaxf(sqrtf(ss), 1e-12f));

    if (c < NB) {
        const int idx = nidx[(size_t)row * NB + c];
        const float* vn = &verts[(size_t)(b * V + idx) * 3];
        const float* vc = &verts[(size_t)row * 3];
        float dx = vn[0] - vc[0], dy = vn[1] - vc[1], dz = vn[2] - vc[2];
        const float inv = 1.f / fmaxf(sqrtf(dx * dx + dy * dy + dz * dz), 1e-12f);
        dx *= inv; dy *= inv; dz *= inv;
        h16x2 xy = { (_Float16)dx, (_Float16)dy };
        h16x2 zw = { (_Float16)dz, (_Float16)wn };
        uint2 h;
        h.x = __builtin_bit_cast(unsigned, xy);
        h.y = __builtin_bit_cast(unsigned, zw);
        tblH[(size_t)row * NB + c] = h;
        tblO[(size_t)row * NB + c] = ((unsigned)idx) << 9;
    }
}

// ---------------------------------------------------------------------------
// Kernel 3 (conv): per wave = one row. Lane halves split neighbor parity
// (lanes<32 even j, lanes>=32 odd j); each lane owns channel pair
// (c0=2m, c0+1) and gathers dwordx4 (16B) -> 25 gathers/wave.
// Software pipeline FORCED with sched_barrier(0): LT(k+4) | C(k) | LG(k+2).
// ---------------------------------------------------------------------------
__global__ __launch_bounds__(256) void conv_kernel(
    const float*    __restrict__ dirs,   // (3, 256)
    const uint2*    __restrict__ tblH,   // (16384, 50)
    const unsigned* __restrict__ tblO,   // (16384, 50)
    const unsigned short* __restrict__ fo_s, // (16384, 64, 4) bf16
    float* __restrict__ out)             // (16384, 64) holds center on entry
{
    const int bid  = blockIdx.x;                     // 0..4095
    const int swz  = ((bid & 7) << 9) + (bid >> 3);  // XCD bijection on 4096
    const int wv   = threadIdx.x >> 6;
    const int l    = threadIdx.x & 63;
    const int row  = swz * 4 + wv;                   // same batch per block
    const int b    = swz >> 10;
    const int half = l >> 5;                         // j parity
    const int m    = l & 31;                         // channel-pair index
    const int c0   = m * 2;

    // normalized direction columns for channels c0, c0+1 (component = support)
    f32x4 cx0, cy0, cz0, cx1, cy1, cz1;
#pragma unroll
    for (int s = 0; s < 4; ++s) {
        const float2 d0 = *reinterpret_cast<const float2*>(&dirs[      s * 64 + c0]);
        const float2 d1 = *reinterpret_cast<const float2*>(&dirs[256 + s * 64 + c0]);
        const float2 d2 = *reinterpret_cast<const float2*>(&dirs[512 + s * 64 + c0]);
        cx0[s] = d0.x; cy0[s] = d1.x; cz0[s] = d2.x;
        cx1[s] = d0.y; cy1[s] = d1.y; cz1[s] = d2.y;
    }
#pragma unroll
    for (int s = 0; s < 4; ++s) {
        const float i0 = 1.f / fmaxf(sqrtf(cx0[s]*cx0[s] + cy0[s]*cy0[s] + cz0[s]*cz0[s]), 1e-12f);
        const float i1 = 1.f / fmaxf(sqrtf(cx1[s]*cx1[s] + cy1[s]*cy1[s] + cz1[s]*cz1[s]), 1e-12f);
        cx0[s] *= i0; cy0[s] *= i0; cz0[s] *= i0;
        cx1[s] *= i1; cy1[s] *= i1; cz1[s] *= i1;
    }

    const uint2*    __restrict__ hrow = tblH + (size_t)row * NB + half;
    const unsigned* __restrict__ orow = tblO + (size_t)row * NB + half;
    const char* baseb = (const char*)fo_s + (size_t)b * ((size_t)V * OC * SUP * 2);
    const unsigned cb = (unsigned)(m << 4);

    uint2    th[5];
    unsigned to[5];
    uint4    gb[3];
    f32x4 acc0 = {0.f, 0.f, 0.f, 0.f}, acc1 = {0.f, 0.f, 0.f, 0.f};

#define LT(k) { th[(k) % 5] = hrow[2 * (k)]; to[(k) % 5] = orow[2 * (k)]; }
#define LG(k) { gb[(k) % 3] = *reinterpret_cast<const uint4*>(baseb + (size_t)(to[(k) % 5] + cb)); }
#define CC(k) { \
        const h16x2 pxy = __builtin_bit_cast(h16x2, th[(k) % 5].x); \
        const h16x2 pzw = __builtin_bit_cast(h16x2, th[(k) % 5].y); \
        const float dx = (float)pxy.x, dy = (float)pxy.y; \
        const float dz = (float)pzw.x, wj = (float)pzw.y; \
        f32x4 t0 = cx0 * dx + cy0 * dy + cz0 * dz; \
        f32x4 t1 = cx1 * dx + cy1 * dy + cz1 * dz; \
        t0.x = fmaxf(t0.x, 0.f); t0.y = fmaxf(t0.y, 0.f); \
        t0.z = fmaxf(t0.z, 0.f); t0.w = fmaxf(t0.w, 0.f); \
        t1.x = fmaxf(t1.x, 0.f); t1.y = fmaxf(t1.y, 0.f); \
        t1.z = fmaxf(t1.z, 0.f); t1.w = fmaxf(t1.w, 0.f); \
        const uint4 g = gb[(k) % 3]; \
        f32x4 f0, f1; \
        f0.x = bflo(g.x); f0.y = bfhi(g.x); f0.z = bflo(g.y); f0.w = bfhi(g.y); \
        f1.x = bflo(g.z); f1.y = bfhi(g.z); f1.z = bflo(g.w); f1.w = bfhi(g.w); \
        acc0 += (t0 * wj) * f0; \
        acc1 += (t1 * wj) * f1; }

    LT(0); LT(1); LT(2); LT(3);
    LG(0); LG(1);
#pragma unroll
    for (int k = 0; k < 25; ++k) {
        if (k + 4 < 25) LT(k + 4);
        __builtin_amdgcn_sched_barrier(0);
        CC(k);
        __builtin_amdgcn_sched_barrier(0);
        if (k + 2 < 25) LG(k + 2);
    }
#undef LT
#undef LG
#undef CC

    // sum supports, then combine even/odd-j halves across lane 32 boundary
    float a0 = acc0.x + acc0.y + acc0.z + acc0.w;
    float a1 = acc1.x + acc1.y + acc1.z + acc1.w;
    a0 += __shfl_xor(a0, 32);
    a1 += __shfl_xor(a1, 32);

    if (l < 32) {
        float* op = &out[(size_t)row * OC + c0];
        const float2 ctr = *reinterpret_cast<const float2*>(op);
        float2 res; res.x = ctr.x + a0; res.y = ctr.y + a1;
        *reinterpret_cast<float2*>(op) = res;
    }
}

// ---------------------------------------------------------------------------
extern "C" void kernel_launch(void* const* d_in, const int* in_sizes, int n_in,
                              void* d_out, int out_size, void* d_ws, size_t ws_size,
                              hipStream_t stream) {
    const int*   nidx  = (const int*)  d_in[0];
    const float* verts = (const float*)d_in[1];
    const float* fm    = (const float*)d_in[2];
    const float* nval  = (const float*)d_in[3];
    const float* W     = (const float*)d_in[4];
    const float* bias  = (const float*)d_in[5];
    const float* dirs  = (const float*)d_in[6];
    float*       out   = (float*)d_out;

    // ws: fo_s 8 MiB | tblH 6.25 MiB | tblO 3.125 MiB  (17.4 MiB total)
    unsigned short* fo_s = (unsigned short*)d_ws;
    uint2*    tblH = (uint2*)   ((char*)d_ws + 8388608);
    unsigned* tblO = (unsigned*)((char*)d_ws + 8388608 + 6553600);

    feat_kernel<<<(BS * V) / 64, 256, 0, stream>>>(fm, W, bias, out, fo_s);
    prep_kernel<<<(BS * V) / 4, 256, 0, stream>>>(nidx, verts, nval, tblH, tblO);
    conv_kernel<<<(BS * V) / 4, 256, 0, stream>>>(dirs, tblH, tblO, fo_s, out);
}